// Round 1
// baseline (209.095 us; speedup 1.0000x reference)
//
#include <hip/hip_runtime.h>
#include <hip/hip_bf16.h>

// out[512, 65536] = inputs[512,256] @ features[65536,256]^T  (fp32 in/out)
// bf16 MFMA GEMM, C = A * B^T with A,B row-major [rows][K=256].
// fp32 -> bf16 conversion fused into LDS staging.

#define M_DIM 512
#define N_DIM 65536
#define K_DIM 256
#define BM 128
#define BN 128
#define BK 64
#define LDK (BK + 8)   // +8 bf16 (16B) pad: breaks 128B row stride, keeps 16B align

typedef __bf16 bf16x8 __attribute__((ext_vector_type(8)));
typedef float f32x4 __attribute__((ext_vector_type(4)));

__global__ __launch_bounds__(256, 2) void hm_gemm_bt(
    const float* __restrict__ A,   // inputs   [M][K]
    const float* __restrict__ B,   // features [N][K]
    float* __restrict__ C)         // out      [M][N]
{
    __shared__ __align__(16) __bf16 As[BM * LDK];
    __shared__ __align__(16) __bf16 Bs[BN * LDK];

    const int tid  = threadIdx.x;
    const int lane = tid & 63;
    const int wave = tid >> 6;            // 4 waves, 2x2 grid of 64x64 subtiles
    const int wm   = (wave >> 1) * 64;
    const int wn   = (wave & 1) * 64;

    const int m0 = blockIdx.x * BM;       // grid.x = 4
    const int n0 = blockIdx.y * BN;       // grid.y = 512

    f32x4 acc[4][4];
    #pragma unroll
    for (int i = 0; i < 4; ++i)
        #pragma unroll
        for (int j = 0; j < 4; ++j)
            acc[i][j] = f32x4{0.f, 0.f, 0.f, 0.f};

    // MFMA 16x16x32 bf16 operand mapping:
    //   a: A[m = lane&15][k = (lane>>4)*8 + j]
    //   b: B^T[n = lane&15][k = (lane>>4)*8 + j]   (features are [N][K])
    //   d: C[row = (lane>>4)*4 + reg][col = lane&15]   (verified m89/m91)
    const int lrow = lane & 15;
    const int lk   = (lane >> 4) * 8;

    for (int k0 = 0; k0 < K_DIM; k0 += BK) {
        // ---- stage A tile: 128x64 fp32 -> bf16.  1024 chunks of 8 elems.
        #pragma unroll
        for (int i = 0; i < 4; ++i) {
            const int c   = i * 256 + tid;      // 0..1023
            const int row = c >> 3;             // BK/8 = 8 chunks per row
            const int kc  = (c & 7) * 8;
            const float* src = A + (m0 + row) * K_DIM + k0 + kc;
            f32x4 v0 = *(const f32x4*)(src);
            f32x4 v1 = *(const f32x4*)(src + 4);
            bf16x8 h;
            h[0] = (__bf16)v0[0]; h[1] = (__bf16)v0[1];
            h[2] = (__bf16)v0[2]; h[3] = (__bf16)v0[3];
            h[4] = (__bf16)v1[0]; h[5] = (__bf16)v1[1];
            h[6] = (__bf16)v1[2]; h[7] = (__bf16)v1[3];
            *(bf16x8*)&As[row * LDK + kc] = h;
        }
        // ---- stage B tile: 128x64 fp32 -> bf16
        #pragma unroll
        for (int i = 0; i < 4; ++i) {
            const int c   = i * 256 + tid;
            const int row = c >> 3;
            const int kc  = (c & 7) * 8;
            const float* src = B + (n0 + row) * K_DIM + k0 + kc;
            f32x4 v0 = *(const f32x4*)(src);
            f32x4 v1 = *(const f32x4*)(src + 4);
            bf16x8 h;
            h[0] = (__bf16)v0[0]; h[1] = (__bf16)v0[1];
            h[2] = (__bf16)v0[2]; h[3] = (__bf16)v0[3];
            h[4] = (__bf16)v1[0]; h[5] = (__bf16)v1[1];
            h[6] = (__bf16)v1[2]; h[7] = (__bf16)v1[3];
            *(bf16x8*)&Bs[row * LDK + kc] = h;
        }
        __syncthreads();

        #pragma unroll
        for (int ks = 0; ks < BK; ks += 32) {
            bf16x8 af[4], bfr[4];
            #pragma unroll
            for (int i = 0; i < 4; ++i)
                af[i] = *(const bf16x8*)&As[(wm + i * 16 + lrow) * LDK + ks + lk];
            #pragma unroll
            for (int j = 0; j < 4; ++j)
                bfr[j] = *(const bf16x8*)&Bs[(wn + j * 16 + lrow) * LDK + ks + lk];
            #pragma unroll
            for (int i = 0; i < 4; ++i)
                #pragma unroll
                for (int j = 0; j < 4; ++j)
                    acc[i][j] = __builtin_amdgcn_mfma_f32_16x16x32_bf16(
                        af[i], bfr[j], acc[i][j], 0, 0, 0);
        }
        __syncthreads();
    }

    // ---- epilogue: C[row = (lane>>4)*4 + r][col = lane&15]
    const int crow = (lane >> 4) * 4;
    const int ccol = lane & 15;
    #pragma unroll
    for (int i = 0; i < 4; ++i) {
        #pragma unroll
        for (int j = 0; j < 4; ++j) {
            float* dst = C + (size_t)(m0 + wm + i * 16 + crow) * N_DIM
                           + (n0 + wn + j * 16 + ccol);
            #pragma unroll
            for (int r = 0; r < 4; ++r)
                dst[(size_t)r * N_DIM] = acc[i][j][r];
        }
    }
}

extern "C" void kernel_launch(void* const* d_in, const int* in_sizes, int n_in,
                              void* d_out, int out_size, void* d_ws, size_t ws_size,
                              hipStream_t stream) {
    // setup_inputs order: inputs, indexes, features, mIoU, IoU
    const float* inputs   = (const float*)d_in[0];
    const float* features = (const float*)d_in[2];
    float* out = (float*)d_out;

    dim3 grid(M_DIM / BM, N_DIM / BN);   // (4, 512): M-tiles adjacent for L2/L3 reuse
    hipLaunchKernelGGL(hm_gemm_bt, grid, dim3(256), 0, stream,
                       inputs, features, out);
}